// Round 3
// baseline (369.442 us; speedup 1.0000x reference)
//
#include <hip/hip_runtime.h>

#define NH 16
#define DM 1024
#define SQ 2048
#define BT 4

typedef __attribute__((ext_vector_type(8))) short bf16x8;
typedef __attribute__((ext_vector_type(4))) short sh4;
typedef __attribute__((ext_vector_type(4))) float f4;
typedef __attribute__((ext_vector_type(4))) float fv4;
typedef unsigned short u16;

#define M2BIAS 23.083120654f   /* 16 * log2(e) */
#define SCALE2 0.18033688f     /* (1/8) * log2(e) */

__device__ __forceinline__ u16 f2bf(float f) {
    union { float f; unsigned u; } v; v.f = f;
    unsigned r = v.u + 0x7FFFu + ((v.u >> 16) & 1u);
    return (u16)(r >> 16);
}

__device__ __forceinline__ float fast_exp2(float x) {
#if __has_builtin(__builtin_amdgcn_exp2f)
    return __builtin_amdgcn_exp2f(x);
#else
    return exp2f(x);
#endif
}

#define GLD16(gp, lp) __builtin_amdgcn_global_load_lds( \
    (const __attribute__((address_space(1))) void*)(gp), \
    (__attribute__((address_space(3))) void*)(lp), 16, 0, 0)

// ---------------- fp32 -> bf16 elementwise (vectorized) ----------------
__global__ __launch_bounds__(256) void cvt_x(const float* __restrict__ x, u16* __restrict__ y) {
    int i = blockIdx.x * 256 + threadIdx.x;
    fv4 v = ((const fv4*)x)[i];
    sh4 r;
    r[0] = (short)f2bf(v[0]); r[1] = (short)f2bf(v[1]);
    r[2] = (short)f2bf(v[2]); r[3] = (short)f2bf(v[3]);
    ((sh4*)y)[i] = r;
}

// ---------------- fp32 W[K][N] -> bf16 Wt[N][K] (LDS transpose) ----------------
__global__ __launch_bounds__(256) void cvt_wT(const float* __restrict__ Wsrc, u16* __restrict__ Wt) {
    __shared__ float t[64][65];
    int r0 = blockIdx.x * 64, c0 = blockIdx.y * 64;
    #pragma unroll
    for (int i = 0; i < 16; ++i) {
        int idx = i * 256 + threadIdx.x;
        int r = idx >> 6, c = idx & 63;
        t[r][c] = Wsrc[(size_t)(r0 + r) * DM + c0 + c];
    }
    __syncthreads();
    #pragma unroll
    for (int i = 0; i < 16; ++i) {
        int idx = i * 256 + threadIdx.x;
        int n = idx >> 6, k = idx & 63;
        Wt[(size_t)(c0 + n) * DM + r0 + k] = f2bf(t[k][n]);
    }
}

// ---------------- mask -> float bias (-M2 for keep, -inf for masked) ----------------
__global__ __launch_bounds__(256) void mk_mbias(const int* __restrict__ mask, float* __restrict__ mb) {
    int i = blockIdx.x * 256 + threadIdx.x;
    mb[i] = mask[i] ? -M2BIAS : -__builtin_inff();
}

// ---------------- projection GEMM: [8192,1024] x [1024,1024] + bias ----------------
__global__ __launch_bounds__(256) void gemm_proj(const u16* __restrict__ A, const u16* __restrict__ Bt,
                                                 const float* __restrict__ bias, u16* __restrict__ outp,
                                                 int vmode) {
    __shared__ u16 As[128 * 64];
    __shared__ u16 Bs[128 * 64];
    int tid = threadIdx.x;
    int w = tid >> 6, lane = tid & 63, quad = lane >> 4, l16 = lane & 15;
    int wm = w >> 1, wn = w & 1;
    int r8 = lane >> 3, cg = (lane & 7) ^ r8;
    const u16* Ag = A + (size_t)blockIdx.x * 128 * DM;
    const u16* Bg = Bt + (size_t)blockIdx.y * 128 * DM;

    f4 acc[4][4];
    #pragma unroll
    for (int mt = 0; mt < 4; ++mt)
        #pragma unroll
        for (int nt = 0; nt < 4; ++nt) acc[mt][nt] = f4{0.f, 0.f, 0.f, 0.f};

    for (int kt = 0; kt < 16; ++kt) {
        int kofs = kt * 64 + cg * 8;
        #pragma unroll
        for (int c = 0; c < 4; ++c) {
            int rbase = w * 32 + c * 8;
            GLD16(Ag + (size_t)(rbase + r8) * DM + kofs, &As[rbase * 64]);
            GLD16(Bg + (size_t)(rbase + r8) * DM + kofs, &Bs[rbase * 64]);
        }
        __syncthreads();
        #pragma unroll
        for (int ks = 0; ks < 2; ++ks) {
            bf16x8 afr[4], bfr[4];
            #pragma unroll
            for (int mt = 0; mt < 4; ++mt) {
                int row = wm * 64 + mt * 16 + l16;
                int ch = (ks * 4 + quad) ^ (row & 7);
                afr[mt] = *(const bf16x8*)&As[row * 64 + ch * 8];
            }
            #pragma unroll
            for (int nt = 0; nt < 4; ++nt) {
                int row = wn * 64 + nt * 16 + l16;
                int ch = (ks * 4 + quad) ^ (row & 7);
                bfr[nt] = *(const bf16x8*)&Bs[row * 64 + ch * 8];
            }
            #pragma unroll
            for (int mt = 0; mt < 4; ++mt)
                #pragma unroll
                for (int nt = 0; nt < 4; ++nt)
                    acc[mt][nt] = __builtin_amdgcn_mfma_f32_16x16x32_bf16(afr[mt], bfr[nt], acc[mt][nt], 0, 0, 0);
        }
        __syncthreads();
    }

    #pragma unroll
    for (int nt = 0; nt < 4; ++nt) {
        int ncol = blockIdx.y * 128 + wn * 64 + nt * 16 + l16;
        float bn = bias[ncol];
        int h = ncol >> 6, d = ncol & 63;
        #pragma unroll
        for (int mt = 0; mt < 4; ++mt) {
            int mbase = blockIdx.x * 128 + wm * 64 + mt * 16 + quad * 4;
            int bidx = mbase >> 11, s0 = mbase & 2047;
            if (vmode == 0) {
                size_t base = ((size_t)bidx * NH + h) * SQ;
                #pragma unroll
                for (int reg = 0; reg < 4; ++reg)
                    outp[(base + s0 + reg) * 64 + d] = f2bf(acc[mt][nt][reg] + bn);
            } else {
                sh4 pk;
                #pragma unroll
                for (int reg = 0; reg < 4; ++reg) pk[reg] = (short)f2bf(acc[mt][nt][reg] + bn);
                *(sh4*)&outp[(((size_t)bidx * NH + h) * 64 + d) * SQ + s0] = pk;
            }
        }
    }
}

// ---------------- flash attention (S^T form) ----------------
// S^T = K*Q^T so each lane's 4 C-regs are 4 consecutive keys of one q-row:
// P writes become packed ds_write_b64 and row-sums accumulate per-lane.
// Split-half pipeline: exp/write keys 0-31 -> PV(kk0) overlaps exp/write keys 32-63.
__global__ __launch_bounds__(256, 3) void attn(const u16* __restrict__ qw, const u16* __restrict__ kw,
                                               const u16* __restrict__ vtw, const float* __restrict__ mbias,
                                               float* __restrict__ outp) {
    __shared__ u16 Ks[2][64 * 64];   // [key][64 d], chunk-swizzled
    __shared__ u16 Vs[2][64 * 64];   // [d][64 keys], chunk-swizzled
    __shared__ short P[4][32 * 72];  // per-wave P tile [qrow][key], row stride 144B
    int tid = threadIdx.x;
    int w = tid >> 6, lane = tid & 63, quad = lane >> 4, l16 = lane & 15;
    int r8 = lane >> 3, sl = lane & 7;
    int bh = blockIdx.x, b = bh >> 4;   // grid.x = bh for XCD L2 locality
    int h = bh & 15;
    int qbase = blockIdx.y * 128 + w * 32;
    const u16* qp = qw + (size_t)bh * SQ * 64;
    const u16* kp = kw + (size_t)bh * SQ * 64;
    const u16* vp = vtw + (size_t)bh * 64 * SQ;
    const float* mbp = mbias + b * SQ;
    short* Pw = (short*)P[w];

    bf16x8 aq[2][2];  // Q frags (B-operand of S^T; layout same as A)
    #pragma unroll
    for (int mt = 0; mt < 2; ++mt)
        #pragma unroll
        for (int ks = 0; ks < 2; ++ks)
            aq[mt][ks] = *(const bf16x8*)&qp[(size_t)(qbase + mt * 16 + l16) * 64 + ks * 32 + quad * 8];

    f4 o[2][4];
    float lrow[2][2];  // [mt][half]: partial row-sum, qrow = mt*16 + l16
    #pragma unroll
    for (int mt = 0; mt < 2; ++mt) {
        #pragma unroll
        for (int nt = 0; nt < 4; ++nt) o[mt][nt] = f4{0.f, 0.f, 0.f, 0.f};
        lrow[mt][0] = 0.f; lrow[mt][1] = 0.f;
    }

    auto stage = [&](int buf, int k0) {
        #pragma unroll
        for (int j = 0; j < 2; ++j) {
            int row = w * 16 + j * 8 + r8;
            int gsl = sl ^ (row & 7);
            GLD16(kp + (size_t)(k0 + row) * 64 + gsl * 8, &Ks[buf][(w * 16 + j * 8) * 64]);
            GLD16(vp + (size_t)row * SQ + k0 + gsl * 8, &Vs[buf][(w * 16 + j * 8) * 64]);
        }
    };

    stage(0, 0);
    #pragma unroll 2
    for (int kb = 0; kb < 32; ++kb) {
        int buf = kb & 1;
        int k0 = kb * 64;
        __syncthreads();  // staging of `buf` done; all waves done reading buf^1
        // mask-bias loads BEFORE the prefetch so their vmcnt wait doesn't drain it
        fv4 bias4[4];
        #pragma unroll
        for (int kt = 0; kt < 4; ++kt)
            bias4[kt] = *(const fv4*)&mbp[k0 + kt * 16 + quad * 4];
        if (kb + 1 < 32) stage(buf ^ 1, k0 + 64);

        // K frags (A-operand of S^T)
        bf16x8 bk[4][2];
        #pragma unroll
        for (int kt = 0; kt < 4; ++kt)
            #pragma unroll
            for (int ks = 0; ks < 2; ++ks) {
                int r = kt * 16 + l16;
                int slot = (ks * 4 + quad) ^ (r & 7);
                bk[kt][ks] = *(const bf16x8*)&Ks[buf][r * 64 + slot * 8];
            }
        // S^T[kt][mt]: rows = keys (quad*4+reg), cols = qrows (l16)
        f4 S[4][2];
        #pragma unroll
        for (int kt = 0; kt < 4; ++kt)
            #pragma unroll
            for (int mt = 0; mt < 2; ++mt) {
                f4 s = f4{0.f, 0.f, 0.f, 0.f};
                s = __builtin_amdgcn_mfma_f32_16x16x32_bf16(bk[kt][0], aq[mt][0], s, 0, 0, 0);
                s = __builtin_amdgcn_mfma_f32_16x16x32_bf16(bk[kt][1], aq[mt][1], s, 0, 0, 0);
                S[kt][mt] = s;
            }
        // two halves: kk=0 uses kt 0,1 (keys 0-31); kk=1 uses kt 2,3
        #pragma unroll
        for (int kk = 0; kk < 2; ++kk) {
            bf16x8 bv[4];
            #pragma unroll
            for (int nt = 0; nt < 4; ++nt) {
                int d = nt * 16 + l16;
                int slot = (kk * 4 + quad) ^ (d & 7);
                bv[nt] = *(const bf16x8*)&Vs[buf][d * 64 + slot * 8];
            }
            #pragma unroll
            for (int kt = kk * 2; kt < kk * 2 + 2; ++kt)
                #pragma unroll
                for (int mt = 0; mt < 2; ++mt) {
                    f4 s = S[kt][mt];
                    float p0 = fast_exp2(s[0] * SCALE2 + bias4[kt][0]);
                    float p1 = fast_exp2(s[1] * SCALE2 + bias4[kt][1]);
                    float p2 = fast_exp2(s[2] * SCALE2 + bias4[kt][2]);
                    float p3 = fast_exp2(s[3] * SCALE2 + bias4[kt][3]);
                    lrow[mt][kk] += (p0 + p1) + (p2 + p3);
                    sh4 pk;
                    pk[0] = (short)(__float_as_uint(p0) >> 16);
                    pk[1] = (short)(__float_as_uint(p1) >> 16);
                    pk[2] = (short)(__float_as_uint(p2) >> 16);
                    pk[3] = (short)(__float_as_uint(p3) >> 16);
                    *(sh4*)&Pw[(mt * 16 + l16) * 72 + kt * 16 + quad * 4] = pk;
                }
            bf16x8 ap[2];
            #pragma unroll
            for (int mt = 0; mt < 2; ++mt)
                ap[mt] = *(const bf16x8*)&Pw[(mt * 16 + l16) * 72 + kk * 32 + quad * 8];
            #pragma unroll
            for (int mt = 0; mt < 2; ++mt)
                #pragma unroll
                for (int nt = 0; nt < 4; ++nt)
                    o[mt][nt] = __builtin_amdgcn_mfma_f32_16x16x32_bf16(ap[mt], bv[nt], o[mt][nt], 0, 0, 0);
        }
    }

    // row sums: reduce across quads, then redistribute to C-layout rows
    #pragma unroll
    for (int mt = 0; mt < 2; ++mt) {
        float v = lrow[mt][0] + lrow[mt][1];
        v += __shfl_xor(v, 16);
        v += __shfl_xor(v, 32);
        #pragma unroll
        for (int reg = 0; reg < 4; ++reg) {
            float inv = 1.f / __shfl(v, quad * 4 + reg);
            int row = qbase + mt * 16 + quad * 4 + reg;
            size_t obase = ((size_t)b * SQ + row) * DM + h * 64;
            #pragma unroll
            for (int nt = 0; nt < 4; ++nt)
                outp[obase + nt * 16 + l16] = o[mt][nt][reg] * inv;
        }
    }
}

extern "C" void kernel_launch(void* const* d_in, const int* in_sizes, int n_in,
                              void* d_out, int out_size, void* d_ws, size_t ws_size,
                              hipStream_t stream) {
    (void)in_sizes; (void)n_in; (void)out_size; (void)ws_size;
    const float* Q  = (const float*)d_in[0];
    const float* K  = (const float*)d_in[1];
    const float* V  = (const float*)d_in[2];
    const int* mask = (const int*)d_in[3];
    const float* Wq = (const float*)d_in[4];
    const float* bq = (const float*)d_in[5];
    const float* Wk = (const float*)d_in[6];
    const float* bk = (const float*)d_in[7];
    const float* Wv = (const float*)d_in[8];
    const float* bv = (const float*)d_in[9];
    float* out = (float*)d_out;
    char* ws = (char*)d_ws;
    u16* q_ws = (u16*)(ws);
    u16* k_ws = (u16*)(ws + (size_t)16 * 1024 * 1024);
    u16* v_ws = (u16*)(ws + (size_t)32 * 1024 * 1024);
    u16* xbuf = (u16*)(ws + (size_t)48 * 1024 * 1024);
    u16* wbuf = (u16*)(ws + (size_t)64 * 1024 * 1024);
    float* mb = (float*)(ws + (size_t)48 * 1024 * 1024);  // reuses xbuf after gemm3

    dim3 gGemm(64, 8), gW(16, 16);
    cvt_x<<<8192, 256, 0, stream>>>(Q, xbuf);
    cvt_wT<<<gW, 256, 0, stream>>>(Wq, wbuf);
    gemm_proj<<<gGemm, 256, 0, stream>>>(xbuf, wbuf, bq, q_ws, 0);
    cvt_x<<<8192, 256, 0, stream>>>(K, xbuf);
    cvt_wT<<<gW, 256, 0, stream>>>(Wk, wbuf);
    gemm_proj<<<gGemm, 256, 0, stream>>>(xbuf, wbuf, bk, k_ws, 0);
    cvt_x<<<8192, 256, 0, stream>>>(V, xbuf);
    cvt_wT<<<gW, 256, 0, stream>>>(Wv, wbuf);
    gemm_proj<<<gGemm, 256, 0, stream>>>(xbuf, wbuf, bv, v_ws, 1);
    mk_mbias<<<32, 256, 0, stream>>>(mask, mb);
    attn<<<dim3(64, 16), 256, 0, stream>>>(q_ws, k_ws, v_ws, mb, out);
}

// Round 4
// 337.910 us; speedup vs baseline: 1.0933x; 1.0933x over previous
//
#include <hip/hip_runtime.h>

#define NH 16
#define DM 1024
#define SQ 2048
#define BT 4

typedef __attribute__((ext_vector_type(8))) short bf16x8;
typedef __attribute__((ext_vector_type(4))) short sh4;
typedef __attribute__((ext_vector_type(4))) float f4;
typedef __attribute__((ext_vector_type(4))) float fv4;
typedef unsigned short u16;

#define M2BIAS 23.083120654f   /* 16 * log2(e) */
#define SCALE2 0.18033688f     /* (1/8) * log2(e) */

__device__ __forceinline__ u16 f2bf(float f) {
    union { float f; unsigned u; } v; v.f = f;
    unsigned r = v.u + 0x7FFFu + ((v.u >> 16) & 1u);
    return (u16)(r >> 16);
}

__device__ __forceinline__ float fast_exp2(float x) {
#if __has_builtin(__builtin_amdgcn_exp2f)
    return __builtin_amdgcn_exp2f(x);
#else
    return exp2f(x);
#endif
}

// 16x16x16 bf16 MFMA (A,B = 4 bf16 / 2 VGPRs per lane): A[m=l16][k=quad*4+j]
#if __has_builtin(__builtin_amdgcn_mfma_f32_16x16x16_bf16)
#define MFMA16(a, b, c) __builtin_amdgcn_mfma_f32_16x16x16_bf16(a, b, c, 0, 0, 0)
#elif __has_builtin(__builtin_amdgcn_mfma_f32_16x16x16bf16_1k)
#define MFMA16(a, b, c) __builtin_amdgcn_mfma_f32_16x16x16bf16_1k(a, b, c, 0, 0, 0)
#else
static __device__ __forceinline__ f4 mfma16_asm(sh4 a, sh4 b, f4 c) {
    asm("v_mfma_f32_16x16x16_bf16 %0, %1, %2, %0" : "+v"(c) : "v"(a), "v"(b));
    return c;
}
#define MFMA16(a, b, c) mfma16_asm(a, b, c)
#endif

#define GLD16(gp, lp) __builtin_amdgcn_global_load_lds( \
    (const __attribute__((address_space(1))) void*)(gp), \
    (__attribute__((address_space(3))) void*)(lp), 16, 0, 0)

// ---------------- fp32 -> bf16 elementwise (vectorized) ----------------
__global__ __launch_bounds__(256) void cvt_x(const float* __restrict__ x, u16* __restrict__ y) {
    int i = blockIdx.x * 256 + threadIdx.x;
    fv4 v = ((const fv4*)x)[i];
    sh4 r;
    r[0] = (short)f2bf(v[0]); r[1] = (short)f2bf(v[1]);
    r[2] = (short)f2bf(v[2]); r[3] = (short)f2bf(v[3]);
    ((sh4*)y)[i] = r;
}

// ---------------- fp32 W[K][N] -> bf16 Wt[N][K] (LDS transpose) ----------------
__global__ __launch_bounds__(256) void cvt_wT(const float* __restrict__ Wsrc, u16* __restrict__ Wt) {
    __shared__ float t[64][65];
    int r0 = blockIdx.x * 64, c0 = blockIdx.y * 64;
    #pragma unroll
    for (int i = 0; i < 16; ++i) {
        int idx = i * 256 + threadIdx.x;
        int r = idx >> 6, c = idx & 63;
        t[r][c] = Wsrc[(size_t)(r0 + r) * DM + c0 + c];
    }
    __syncthreads();
    #pragma unroll
    for (int i = 0; i < 16; ++i) {
        int idx = i * 256 + threadIdx.x;
        int n = idx >> 6, k = idx & 63;
        Wt[(size_t)(c0 + n) * DM + r0 + k] = f2bf(t[k][n]);
    }
}

// ---------------- mask -> float bias (-M2 for keep, -inf for masked) ----------------
__global__ __launch_bounds__(256) void mk_mbias(const int* __restrict__ mask, float* __restrict__ mb) {
    int i = blockIdx.x * 256 + threadIdx.x;
    mb[i] = mask[i] ? -M2BIAS : -__builtin_inff();
}

// ---------------- projection GEMM: [8192,1024] x [1024,1024] + bias ----------------
__global__ __launch_bounds__(256) void gemm_proj(const u16* __restrict__ A, const u16* __restrict__ Bt,
                                                 const float* __restrict__ bias, u16* __restrict__ outp,
                                                 int vmode) {
    __shared__ u16 As[128 * 64];
    __shared__ u16 Bs[128 * 64];
    int tid = threadIdx.x;
    int w = tid >> 6, lane = tid & 63, quad = lane >> 4, l16 = lane & 15;
    int wm = w >> 1, wn = w & 1;
    int r8 = lane >> 3, cg = (lane & 7) ^ r8;
    const u16* Ag = A + (size_t)blockIdx.x * 128 * DM;
    const u16* Bg = Bt + (size_t)blockIdx.y * 128 * DM;

    f4 acc[4][4];
    #pragma unroll
    for (int mt = 0; mt < 4; ++mt)
        #pragma unroll
        for (int nt = 0; nt < 4; ++nt) acc[mt][nt] = f4{0.f, 0.f, 0.f, 0.f};

    for (int kt = 0; kt < 16; ++kt) {
        int kofs = kt * 64 + cg * 8;
        #pragma unroll
        for (int c = 0; c < 4; ++c) {
            int rbase = w * 32 + c * 8;
            GLD16(Ag + (size_t)(rbase + r8) * DM + kofs, &As[rbase * 64]);
            GLD16(Bg + (size_t)(rbase + r8) * DM + kofs, &Bs[rbase * 64]);
        }
        __syncthreads();
        #pragma unroll
        for (int ks = 0; ks < 2; ++ks) {
            bf16x8 afr[4], bfr[4];
            #pragma unroll
            for (int mt = 0; mt < 4; ++mt) {
                int row = wm * 64 + mt * 16 + l16;
                int ch = (ks * 4 + quad) ^ (row & 7);
                afr[mt] = *(const bf16x8*)&As[row * 64 + ch * 8];
            }
            #pragma unroll
            for (int nt = 0; nt < 4; ++nt) {
                int row = wn * 64 + nt * 16 + l16;
                int ch = (ks * 4 + quad) ^ (row & 7);
                bfr[nt] = *(const bf16x8*)&Bs[row * 64 + ch * 8];
            }
            #pragma unroll
            for (int mt = 0; mt < 4; ++mt)
                #pragma unroll
                for (int nt = 0; nt < 4; ++nt)
                    acc[mt][nt] = __builtin_amdgcn_mfma_f32_16x16x32_bf16(afr[mt], bfr[nt], acc[mt][nt], 0, 0, 0);
        }
        __syncthreads();
    }

    #pragma unroll
    for (int nt = 0; nt < 4; ++nt) {
        int ncol = blockIdx.y * 128 + wn * 64 + nt * 16 + l16;
        float bn = bias[ncol];
        int h = ncol >> 6, d = ncol & 63;
        #pragma unroll
        for (int mt = 0; mt < 4; ++mt) {
            int mbase = blockIdx.x * 128 + wm * 64 + mt * 16 + quad * 4;
            int bidx = mbase >> 11, s0 = mbase & 2047;
            if (vmode == 0) {
                size_t base = ((size_t)bidx * NH + h) * SQ;
                #pragma unroll
                for (int reg = 0; reg < 4; ++reg)
                    outp[(base + s0 + reg) * 64 + d] = f2bf(acc[mt][nt][reg] + bn);
            } else {
                sh4 pk;
                #pragma unroll
                for (int reg = 0; reg < 4; ++reg) pk[reg] = (short)f2bf(acc[mt][nt][reg] + bn);
                *(sh4*)&outp[(((size_t)bidx * NH + h) * 64 + d) * SQ + s0] = pk;
            }
        }
    }
}

// ---------------- flash attention (S^T form, register-resident P) ----------------
// S^T = K*Q^T: lane(quad,l16) C-regs = keys 4*quad+r for q-row l16 — this IS the
// A-operand layout of mfma 16x16x16 (A[m=l16][k=quad*4+j]). PV therefore consumes
// P straight from registers (no LDS round-trip, no P array): per 16-key tile kt,
// one K=16 MFMA per (mt,nt) with B = V^T[d][4 consecutive keys] (ds_read_b64).
__global__ __launch_bounds__(256, 4) void attn(const u16* __restrict__ qw, const u16* __restrict__ kw,
                                               const u16* __restrict__ vtw, const float* __restrict__ mbias,
                                               float* __restrict__ outp) {
    __shared__ u16 Ks[2][64 * 64];   // [key][64 d], 16B-chunk XOR swizzled
    __shared__ u16 Vs[2][64 * 64];   // [d][64 keys], 16B-chunk XOR swizzled
    int tid = threadIdx.x;
    int w = tid >> 6, lane = tid & 63, quad = lane >> 4, l16 = lane & 15;
    int r8 = lane >> 3, sl = lane & 7;
    int bh = blockIdx.x, b = bh >> 4;   // grid.x = bh for XCD L2 locality
    int h = bh & 15;
    int qbase = blockIdx.y * 128 + w * 32;
    const u16* qp = qw + (size_t)bh * SQ * 64;
    const u16* kp = kw + (size_t)bh * SQ * 64;
    const u16* vp = vtw + (size_t)bh * 64 * SQ;
    const float* mbp = mbias + b * SQ;

    bf16x8 aq[2][2];  // Q frags (B-operand of S^T)
    #pragma unroll
    for (int mt = 0; mt < 2; ++mt)
        #pragma unroll
        for (int ks = 0; ks < 2; ++ks)
            aq[mt][ks] = *(const bf16x8*)&qp[(size_t)(qbase + mt * 16 + l16) * 64 + ks * 32 + quad * 8];

    f4 o[2][4];
    float lrow[2] = {0.f, 0.f};  // per-lane partial row-sum for q-row l16
    #pragma unroll
    for (int mt = 0; mt < 2; ++mt)
        #pragma unroll
        for (int nt = 0; nt < 4; ++nt) o[mt][nt] = f4{0.f, 0.f, 0.f, 0.f};

    auto stage = [&](int buf, int k0) {
        #pragma unroll
        for (int j = 0; j < 2; ++j) {
            int row = w * 16 + j * 8 + r8;
            int gsl = sl ^ (row & 7);
            GLD16(kp + (size_t)(k0 + row) * 64 + gsl * 8, &Ks[buf][(w * 16 + j * 8) * 64]);
            GLD16(vp + (size_t)row * SQ + k0 + gsl * 8, &Vs[buf][(w * 16 + j * 8) * 64]);
        }
    };

    stage(0, 0);
    for (int kb = 0; kb < 32; ++kb) {
        int buf = kb & 1;
        int k0 = kb * 64;
        __syncthreads();  // staging of `buf` done; all waves done reading buf^1
        // mask-bias loads BEFORE the prefetch so their vmcnt wait doesn't drain it
        fv4 bias4[4];
        #pragma unroll
        for (int kt = 0; kt < 4; ++kt)
            bias4[kt] = *(const fv4*)&mbp[k0 + kt * 16 + quad * 4];
        if (kb + 1 < 32) stage(buf ^ 1, k0 + 64);

        // K frags (A-operand of S^T)
        bf16x8 bk[4][2];
        #pragma unroll
        for (int kt = 0; kt < 4; ++kt)
            #pragma unroll
            for (int ks = 0; ks < 2; ++ks) {
                int r = kt * 16 + l16;
                int slot = (ks * 4 + quad) ^ (r & 7);
                bk[kt][ks] = *(const bf16x8*)&Ks[buf][r * 64 + slot * 8];
            }
        // S^T[kt][mt]: lane(quad,l16) regs = keys 16kt+4quad+r, q-row = l16
        f4 S[4][2];
        #pragma unroll
        for (int kt = 0; kt < 4; ++kt)
            #pragma unroll
            for (int mt = 0; mt < 2; ++mt) {
                f4 s = f4{0.f, 0.f, 0.f, 0.f};
                s = __builtin_amdgcn_mfma_f32_16x16x32_bf16(bk[kt][0], aq[mt][0], s, 0, 0, 0);
                s = __builtin_amdgcn_mfma_f32_16x16x32_bf16(bk[kt][1], aq[mt][1], s, 0, 0, 0);
                S[kt][mt] = s;
            }
        // per 16-key tile: exp -> pack (registers) -> V^T b64 frags -> K=16 PV MFMAs
        #pragma unroll
        for (int kt = 0; kt < 4; ++kt) {
            sh4 pa[2];
            #pragma unroll
            for (int mt = 0; mt < 2; ++mt) {
                f4 s = S[kt][mt];
                float p0 = fast_exp2(s[0] * SCALE2 + bias4[kt][0]);
                float p1 = fast_exp2(s[1] * SCALE2 + bias4[kt][1]);
                float p2 = fast_exp2(s[2] * SCALE2 + bias4[kt][2]);
                float p3 = fast_exp2(s[3] * SCALE2 + bias4[kt][3]);
                lrow[mt] += (p0 + p1) + (p2 + p3);
                pa[mt][0] = (short)(__float_as_uint(p0) >> 16);
                pa[mt][1] = (short)(__float_as_uint(p1) >> 16);
                pa[mt][2] = (short)(__float_as_uint(p2) >> 16);
                pa[mt][3] = (short)(__float_as_uint(p3) >> 16);
            }
            sh4 bv[4];
            #pragma unroll
            for (int nt = 0; nt < 4; ++nt) {
                int row = nt * 16 + l16;  // d
                int ch = (2 * kt + (quad >> 1)) ^ (row & 7);
                bv[nt] = *(const sh4*)&Vs[buf][row * 64 + ch * 8 + (quad & 1) * 4];
            }
            #pragma unroll
            for (int mt = 0; mt < 2; ++mt)
                #pragma unroll
                for (int nt = 0; nt < 4; ++nt)
                    o[mt][nt] = MFMA16(pa[mt], bv[nt], o[mt][nt]);
        }
    }

    // row sums: each q-row l16's partials live in the 4 quads; reduce, redistribute
    #pragma unroll
    for (int mt = 0; mt < 2; ++mt) {
        float v = lrow[mt];
        v += __shfl_xor(v, 16);
        v += __shfl_xor(v, 32);
        #pragma unroll
        for (int reg = 0; reg < 4; ++reg) {
            float inv = 1.f / __shfl(v, quad * 4 + reg);
            int row = qbase + mt * 16 + quad * 4 + reg;
            size_t obase = ((size_t)b * SQ + row) * DM + h * 64;
            #pragma unroll
            for (int nt = 0; nt < 4; ++nt)
                outp[obase + nt * 16 + l16] = o[mt][nt][reg] * inv;
        }
    }
}

extern "C" void kernel_launch(void* const* d_in, const int* in_sizes, int n_in,
                              void* d_out, int out_size, void* d_ws, size_t ws_size,
                              hipStream_t stream) {
    (void)in_sizes; (void)n_in; (void)out_size; (void)ws_size;
    const float* Q  = (const float*)d_in[0];
    const float* K  = (const float*)d_in[1];
    const float* V  = (const float*)d_in[2];
    const int* mask = (const int*)d_in[3];
    const float* Wq = (const float*)d_in[4];
    const float* bq = (const float*)d_in[5];
    const float* Wk = (const float*)d_in[6];
    const float* bk = (const float*)d_in[7];
    const float* Wv = (const float*)d_in[8];
    const float* bv = (const float*)d_in[9];
    float* out = (float*)d_out;
    char* ws = (char*)d_ws;
    u16* q_ws = (u16*)(ws);
    u16* k_ws = (u16*)(ws + (size_t)16 * 1024 * 1024);
    u16* v_ws = (u16*)(ws + (size_t)32 * 1024 * 1024);
    u16* xbuf = (u16*)(ws + (size_t)48 * 1024 * 1024);
    u16* wbuf = (u16*)(ws + (size_t)64 * 1024 * 1024);
    float* mb = (float*)(ws + (size_t)48 * 1024 * 1024);  // reuses xbuf after gemm3

    dim3 gGemm(64, 8), gW(16, 16);
    cvt_x<<<8192, 256, 0, stream>>>(Q, xbuf);
    cvt_wT<<<gW, 256, 0, stream>>>(Wq, wbuf);
    gemm_proj<<<gGemm, 256, 0, stream>>>(xbuf, wbuf, bq, q_ws, 0);
    cvt_x<<<8192, 256, 0, stream>>>(K, xbuf);
    cvt_wT<<<gW, 256, 0, stream>>>(Wk, wbuf);
    gemm_proj<<<gGemm, 256, 0, stream>>>(xbuf, wbuf, bk, k_ws, 0);
    cvt_x<<<8192, 256, 0, stream>>>(V, xbuf);
    cvt_wT<<<gW, 256, 0, stream>>>(Wv, wbuf);
    gemm_proj<<<gGemm, 256, 0, stream>>>(xbuf, wbuf, bv, v_ws, 1);
    mk_mbias<<<32, 256, 0, stream>>>(mask, mb);
    attn<<<dim3(64, 16), 256, 0, stream>>>(q_ws, k_ws, v_ws, mb, out);
}